// Round 5
// baseline (175.344 us; speedup 1.0000x reference)
//
#include <hip/hip_runtime.h>
#include <math.h>

#define BB 64
#define CC 128
#define KK 64
#define NN 4096
#define PCH 128            // pixels per chunk
#define NCH 4              // chunks per block
#define SLAB (PCH*NCH)     // 512 pixels per block

typedef __attribute__((ext_vector_type(8))) short short8;
typedef __attribute__((ext_vector_type(16))) float f32x16;

// fp32 -> bf16 bits, round-to-nearest-even
__device__ __forceinline__ unsigned f2bf(float f) {
    unsigned u = __float_as_uint(f);
    return (u + 0x7fffu + ((u >> 16) & 1u)) >> 16;
}

__device__ __forceinline__ short8 pack8(float4 a, float4 b) {
    short8 r;
    r[0]=(short)f2bf(a.x); r[1]=(short)f2bf(a.y); r[2]=(short)f2bf(a.z); r[3]=(short)f2bf(a.w);
    r[4]=(short)f2bf(b.x); r[5]=(short)f2bf(b.y); r[6]=(short)f2bf(b.z); r[7]=(short)f2bf(b.w);
    return r;
}

// LDS-only fence barrier: drains ds ops for cross-wave visibility but leaves
// global loads (vmcnt) in flight across the barrier (prefetch survives).
#define LDS_FENCE_BARRIER() do {                                  \
    asm volatile("s_waitcnt lgkmcnt(0)" ::: "memory");            \
    __builtin_amdgcn_s_barrier();                                 \
} while (0)

// ---------------- Phase 1: logits -> softmax -> vlad partials (MFMA bf16) ----
// MFMA 32x32x16 layouts (verified in round 2, absmax 1.2e-4 PASS):
//   A[m][k]: lane m=l&31, k=8*(l>>5)+j ; B[k][n]: lane n=l&31, k=8*(l>>5)+j
//   C/D: col=l&31, row=(r&3)+8*(r>>2)+4*(l>>5)
// LDS 16B-chunk XOR swizzle: chunk' = chunk ^ (row & 7)
__global__ __launch_bounds__(512, 4) void nv_phase1(
    const float* __restrict__ x,      // [B][C][N]
    const float* __restrict__ convw,  // [K][C]
    float* __restrict__ vlad,         // [B][K][C] accumulated via atomics (d_out)
    float* __restrict__ asum_g)       // [B][K]    accumulated via atomics (ws)
{
    __shared__ alignas(16) unsigned short xs[PCH*CC];  // 32 KB bf16 x, [n][c], swizzled
    __shared__ alignas(16) unsigned short xc[CC*PCH];  // 32 KB bf16 x, [c][n], swizzled
    __shared__ float redsm[2][PCH];                    // softmax denom cross-wave
    __shared__ float asred[2][2][16][4];               // [kt][q][r][nt]

    unsigned short* al = xs;   // a[k][n] bf16 (16 KB) aliases xs rows 0..63:
                               // xs dead after logits; al dead before next stage.

    const int t  = threadIdx.x;
    const int b  = blockIdx.y;
    const int n_slab = blockIdx.x * SLAB;
    const int l   = t & 63;
    const int wid = t >> 6;
    const int ln  = l & 31;
    const int q   = l >> 5;
    const int kt  = wid & 1;          // logits k-tile
    const int nt  = wid >> 1;         // logits n-tile
    const int ct  = wid & 3;          // vlad c-tile
    const int kt2 = wid >> 2;         // vlad k-tile
    const int r4  = t & 3;

    const float* xb = x + (size_t)b * CC * NN;
    const int n_ = ln + 32*nt;        // softmax pixel (chunk-local)
    const int c2 = ln + 32*ct;        // vlad A row (channel)
    const int k2 = ln + 32*kt2;       // vlad B row (cluster)

    // ---- prologue: issue chunk-0 staging loads (held packed in regs) ----
    unsigned pf0[8], pf1[8];
#pragma unroll
    for (int i = 0; i < 8; ++i) {
        int u = (t >> 2) + 128 * i, cQ = u >> 5, nQ = u & 31;
        float4 v = *(const float4*)(xb + (size_t)(4*cQ + r4) * NN + n_slab + 4*nQ);
        pf0[i] = f2bf(v.x) | (f2bf(v.y) << 16);
        pf1[i] = f2bf(v.z) | (f2bf(v.w) << 16);
    }

    // ---- preload conv_w fragments (A of logits), reused for all chunks ----
    short8 wfrag[8];
    {
        const float* wr = convw + (size_t)(ln + 32*kt) * CC + 8*q;
#pragma unroll
        for (int cs = 0; cs < 8; ++cs) {
            float4 a  = *(const float4*)(wr + 16*cs);
            float4 bb = *(const float4*)(wr + 16*cs + 4);
            wfrag[cs] = pack8(a, bb);
        }
    }

    f32x16 vacc;
#pragma unroll
    for (int i = 0; i < 16; ++i) vacc[i] = 0.f;
    float asum_l[16];
#pragma unroll
    for (int i = 0; i < 16; ++i) asum_l[i] = 0.f;

#pragma unroll 1
    for (int chk = 0; chk < NCH; ++chk) {
        // ---- A: write xs[n][c] + xc[c][n] from prefetch regs ----
#pragma unroll
        for (int i = 0; i < 8; ++i) {
            int u = (t >> 2) + 128 * i, cQ = u >> 5, nQ = u & 31;
            unsigned d0 = pf0[i], d1 = pf1[i];
            // xc: straight write, 4 consecutive n at row c
            int c = 4*cQ + r4;
            *(uint2*)((char*)xc + c*256 + ((((nQ >> 1) ^ (c & 7)) << 4) | ((nQ & 1) * 8)))
                = make_uint2(d0, d1);
            // xs: quad 4x4 shuffle transpose (verified round 2)
            unsigned q0 = (unsigned)__shfl_xor((int)d0, 1);
            unsigned q1 = (unsigned)__shfl_xor((int)d1, 1);
            unsigned e, f;
            if (r4 & 1) { e = (q0 >> 16) | (d0 & 0xffff0000u);
                          f = (q1 >> 16) | (d1 & 0xffff0000u); }
            else        { e = (d0 & 0xffffu) | (q0 << 16);
                          f = (d1 & 0xffffu) | (q1 << 16); }
            unsigned s2 = (unsigned)__shfl_xor((int)((r4 & 2) ? e : f), 2);
            unsigned w0 = (r4 & 2) ? s2 : e;
            unsigned w1 = (r4 & 2) ? f : s2;
            int nn  = 4*nQ + r4;
            int chp = (cQ >> 1) ^ (nn & 7);
            *(uint2*)((char*)xs + nn*256 + (chp << 4) + (cQ & 1)*8) = make_uint2(w0, w1);
        }
        // ---- B: issue next chunk's staging loads (hidden under C/D/E/F) ----
        if (chk + 1 < NCH) {
            const int gn1 = n_slab + (chk + 1) * PCH;
#pragma unroll
            for (int i = 0; i < 8; ++i) {
                int u = (t >> 2) + 128 * i, cQ = u >> 5, nQ = u & 31;
                float4 v = *(const float4*)(xb + (size_t)(4*cQ + r4) * NN + gn1 + 4*nQ);
                pf0[i] = f2bf(v.x) | (f2bf(v.y) << 16);
                pf1[i] = f2bf(v.z) | (f2bf(v.w) << 16);
            }
        }
        LDS_FENCE_BARRIER();   // #1: xs, xc visible

        // ---- C: logits D[k][n] = W x X ----
        f32x16 lacc;
#pragma unroll
        for (int i = 0; i < 16; ++i) lacc[i] = 0.f;
#pragma unroll
        for (int cs = 0; cs < 8; ++cs) {
            int chp = (2*cs + q) ^ (n_ & 7);
            short8 bf = *(const short8*)((const char*)xs + n_*256 + (chp << 4));
            lacc = __builtin_amdgcn_mfma_f32_32x32x16_bf16(wfrag[cs], bf, lacc, 0, 0, 0);
        }

        // ---- D: softmax over k, no max-sub (|logit| <~ 8, exp safe in fp32) ----
        float ssum = 0.f;
#pragma unroll
        for (int i = 0; i < 16; ++i) { float e2 = __expf(lacc[i]); lacc[i] = e2; ssum += e2; }
        ssum += __shfl_xor(ssum, 32);
        if (q == 0) redsm[kt][n_] = ssum;
        LDS_FENCE_BARRIER();   // #2: denom visible

        // ---- E: scale, store a -> al (aliased), accumulate asum ----
        float inv = 1.0f / (redsm[0][n_] + redsm[1][n_]);
#pragma unroll
        for (int i = 0; i < 16; ++i) {
            float a = lacc[i] * inv;
            asum_l[i] += a;
            int k_ = 32*kt + 4*q + (i & 3) + 8*(i >> 2);
            al[k_*128 + ((((n_ >> 3) ^ (k_ & 7)) << 3) | (n_ & 7))] = (unsigned short)f2bf(a);
        }
        LDS_FENCE_BARRIER();   // #3: al ready

        // ---- F: vlad D[c][k] += X x A^T, both operands from LDS ----
#pragma unroll
        for (int ns = 0; ns < 8; ++ns) {
            int ca = (2*ns + q) ^ (c2 & 7);
            short8 af = *(const short8*)((const char*)xc + c2*256 + (ca << 4));
            int cb = (2*ns + q) ^ (k2 & 7);
            short8 bf = *(const short8*)((const char*)al + k2*256 + (cb << 4));
            vacc = __builtin_amdgcn_mfma_f32_32x32x16_bf16(af, bf, vacc, 0, 0, 0);
        }
        LDS_FENCE_BARRIER();   // #4: LDS free for next chunk's staging writes
    }

    // ---- epilogue: vlad partials -> global atomics ----
    {
        float* vb = vlad + (size_t)b * KK * CC + (size_t)k2 * CC + 32*ct + 4*q;
#pragma unroll
        for (int i = 0; i < 16; ++i)
            atomicAdd(&vb[(i & 3) + 8*(i >> 2)], vacc[i]);
    }

    // ---- asum: butterfly over 32 pixel-lanes, cross-wave LDS, 64 atomics ----
#pragma unroll
    for (int i = 0; i < 16; ++i) {
        float v = asum_l[i];
        v += __shfl_xor(v, 1);  v += __shfl_xor(v, 2);  v += __shfl_xor(v, 4);
        v += __shfl_xor(v, 8);  v += __shfl_xor(v, 16);
        asum_l[i] = v;
    }
    if (ln == 0) {
#pragma unroll
        for (int i = 0; i < 16; ++i) asred[kt][q][i][nt] = asum_l[i];
    }
    __syncthreads();
    if (t < 64) {
        int kt_ = t >> 5, q_ = (t >> 4) & 1, r_ = t & 15;
        int k_ = 32*kt_ + 4*q_ + (r_ & 3) + 8*(r_ >> 2);
        float s = asred[kt_][q_][r_][0] + asred[kt_][q_][r_][1]
                + asred[kt_][q_][r_][2] + asred[kt_][q_][r_][3];
        atomicAdd(&asum_g[b * KK + k_], s);
    }
}

// ---------------- Phase 2: centroid subtract + intra + global L2 normalize ---
__global__ __launch_bounds__(256) void nv_phase2(
    float* __restrict__ vlad,        // [B][K][C] in/out (d_out)
    const float* __restrict__ asum,  // [B][K]
    const float* __restrict__ cent)  // [K][C]
{
    __shared__ float gred[4];
    const int b    = blockIdx.x;
    const int w    = threadIdx.x >> 6;   // wave 0..3 -> 16 rows each
    const int lane = threadIdx.x & 63;

    float v[32];
    float gsum = 0.f;
#pragma unroll
    for (int r = 0; r < 16; r++) {
        int k = w * 16 + r;
        float a  = asum[b * KK + k];
        float x0 = vlad[((size_t)b * KK + k) * CC + lane]      - a * cent[k * CC + lane];
        float x1 = vlad[((size_t)b * KK + k) * CC + lane + 64] - a * cent[k * CC + lane + 64];
        float ss = x0 * x0 + x1 * x1;
#pragma unroll
        for (int m = 1; m < 64; m <<= 1) ss += __shfl_xor(ss, m, 64);
        float rn = 1.0f / fmaxf(sqrtf(ss), 1e-12f);
        v[2 * r]     = x0 * rn;
        v[2 * r + 1] = x1 * rn;
        gsum += ss * rn * rn;
    }
    if (lane == 0) gred[w] = gsum;
    __syncthreads();
    float g  = gred[0] + gred[1] + gred[2] + gred[3];
    float gs = 1.0f / fmaxf(sqrtf(g), 1e-12f);
#pragma unroll
    for (int r = 0; r < 16; r++) {
        int k = w * 16 + r;
        vlad[((size_t)b * KK + k) * CC + lane]      = v[2 * r]     * gs;
        vlad[((size_t)b * KK + k) * CC + lane + 64] = v[2 * r + 1] * gs;
    }
}

extern "C" void kernel_launch(void* const* d_in, const int* in_sizes, int n_in,
                              void* d_out, int out_size, void* d_ws, size_t ws_size,
                              hipStream_t stream) {
    const float* x     = (const float*)d_in[0];
    const float* convw = (const float*)d_in[1];
    const float* cent  = (const float*)d_in[2];
    float* out  = (float*)d_out;
    float* asum = (float*)d_ws;   // B*K floats = 16 KiB

    hipMemsetAsync(out,  0, (size_t)BB * KK * CC * sizeof(float), stream);
    hipMemsetAsync(asum, 0, (size_t)BB * KK * sizeof(float), stream);

    nv_phase1<<<dim3(NN / SLAB, BB), 512, 0, stream>>>(x, convw, out, asum);
    nv_phase2<<<BB, 256, 0, stream>>>(out, asum, cent);
}

// Round 6
// 159.088 us; speedup vs baseline: 1.1022x; 1.1022x over previous
//
#include <hip/hip_runtime.h>
#include <math.h>

#define BB 64
#define CC 128
#define KK 64
#define NN 4096
#define PCH 128            // pixels per chunk
#define NCH 4              // chunks per block
#define SLAB (PCH*NCH)     // 512 pixels per block

typedef __attribute__((ext_vector_type(8))) short short8;
typedef __attribute__((ext_vector_type(16))) float f32x16;

// fp32 -> bf16 bits, round-to-nearest-even
__device__ __forceinline__ unsigned f2bf(float f) {
    unsigned u = __float_as_uint(f);
    return (u + 0x7fffu + ((u >> 16) & 1u)) >> 16;
}

__device__ __forceinline__ short8 pack8(float4 a, float4 b) {
    short8 r;
    r[0]=(short)f2bf(a.x); r[1]=(short)f2bf(a.y); r[2]=(short)f2bf(a.z); r[3]=(short)f2bf(a.w);
    r[4]=(short)f2bf(b.x); r[5]=(short)f2bf(b.y); r[6]=(short)f2bf(b.z); r[7]=(short)f2bf(b.w);
    return r;
}

// LDS-only fence barrier: drains ds ops for cross-wave visibility but leaves
// global loads (vmcnt) in flight across the barrier (prefetch survives).
#define LDS_FENCE_BARRIER() do {                                  \
    asm volatile("s_waitcnt lgkmcnt(0)" ::: "memory");            \
    __builtin_amdgcn_s_barrier();                                 \
} while (0)

// ---------------- Phase 1: logits -> softmax -> vlad partials (MFMA bf16) ----
// MFMA 32x32x16 layouts (verified in round 2, absmax 1.2e-4 PASS):
//   A[m][k]: lane m=l&31, k=8*(l>>5)+j ; B[k][n]: lane n=l&31, k=8*(l>>5)+j
//   C/D: col=l&31, row=(r&3)+8*(r>>2)+4*(l>>5)
// LDS 16B-chunk XOR swizzle: chunk' = chunk ^ (row & 7)
// launch_bounds (512,2): 256-reg unified cap -> no scratch spills (round-5 fix);
// 1 block/CU (LDS 66KB also caps at 2), latency hidden by cross-chunk prefetch.
__global__ __launch_bounds__(512, 2) void nv_phase1(
    const float* __restrict__ x,      // [B][C][N]
    const float* __restrict__ convw,  // [K][C]
    float* __restrict__ vlad,         // [B][K][C] accumulated via atomics (d_out)
    float* __restrict__ asum_g)       // [B][K]    accumulated via atomics (ws)
{
    __shared__ alignas(16) unsigned short xs[PCH*CC];  // 32 KB bf16 x, [n][c], swizzled
    __shared__ alignas(16) unsigned short xc[CC*PCH];  // 32 KB bf16 x, [c][n], swizzled
    __shared__ float redsm[2][PCH];                    // softmax denom cross-wave
    __shared__ float asred[2][2][16][4];               // [kt][q][r][nt]

    unsigned short* al = xs;   // a[k][n] bf16 (16 KB) aliases xs rows 0..63:
                               // xs dead after logits; al dead before next stage.

    const int t  = threadIdx.x;
    const int b  = blockIdx.y;
    const int n_slab = blockIdx.x * SLAB;
    const int l   = t & 63;
    const int wid = t >> 6;
    const int ln  = l & 31;
    const int q   = l >> 5;
    const int kt  = wid & 1;          // logits k-tile
    const int nt  = wid >> 1;         // logits n-tile
    const int ct  = wid & 3;          // vlad c-tile
    const int kt2 = wid >> 2;         // vlad k-tile
    const int r4  = t & 3;

    const float* xb = x + (size_t)b * CC * NN;
    const int n_ = ln + 32*nt;        // softmax pixel (chunk-local)
    const int c2 = ln + 32*ct;        // vlad A row (channel)
    const int k2 = ln + 32*kt2;       // vlad B row (cluster)

    // ---- prologue: issue chunk-0 staging loads (held packed in regs) ----
    unsigned pf0[8], pf1[8];
#pragma unroll
    for (int i = 0; i < 8; ++i) {
        int u = (t >> 2) + 128 * i, cQ = u >> 5, nQ = u & 31;
        float4 v = *(const float4*)(xb + (size_t)(4*cQ + r4) * NN + n_slab + 4*nQ);
        pf0[i] = f2bf(v.x) | (f2bf(v.y) << 16);
        pf1[i] = f2bf(v.z) | (f2bf(v.w) << 16);
    }

    // ---- preload conv_w fragments (A of logits), reused for all chunks ----
    short8 wfrag[8];
    {
        const float* wr = convw + (size_t)(ln + 32*kt) * CC + 8*q;
#pragma unroll
        for (int cs = 0; cs < 8; ++cs) {
            float4 a  = *(const float4*)(wr + 16*cs);
            float4 bb = *(const float4*)(wr + 16*cs + 4);
            wfrag[cs] = pack8(a, bb);
        }
    }

    f32x16 vacc;
#pragma unroll
    for (int i = 0; i < 16; ++i) vacc[i] = 0.f;
    float asum_l[16];
#pragma unroll
    for (int i = 0; i < 16; ++i) asum_l[i] = 0.f;

#pragma unroll 1
    for (int chk = 0; chk < NCH; ++chk) {
        // ---- A: write xs[n][c] + xc[c][n] from prefetch regs ----
#pragma unroll
        for (int i = 0; i < 8; ++i) {
            int u = (t >> 2) + 128 * i, cQ = u >> 5, nQ = u & 31;
            unsigned d0 = pf0[i], d1 = pf1[i];
            // xc: straight write, 4 consecutive n at row c
            int c = 4*cQ + r4;
            *(uint2*)((char*)xc + c*256 + ((((nQ >> 1) ^ (c & 7)) << 4) | ((nQ & 1) * 8)))
                = make_uint2(d0, d1);
            // xs: quad 4x4 shuffle transpose (verified round 2)
            unsigned q0 = (unsigned)__shfl_xor((int)d0, 1);
            unsigned q1 = (unsigned)__shfl_xor((int)d1, 1);
            unsigned e, f;
            if (r4 & 1) { e = (q0 >> 16) | (d0 & 0xffff0000u);
                          f = (q1 >> 16) | (d1 & 0xffff0000u); }
            else        { e = (d0 & 0xffffu) | (q0 << 16);
                          f = (d1 & 0xffffu) | (q1 << 16); }
            unsigned s2 = (unsigned)__shfl_xor((int)((r4 & 2) ? e : f), 2);
            unsigned w0 = (r4 & 2) ? s2 : e;
            unsigned w1 = (r4 & 2) ? f : s2;
            int nn  = 4*nQ + r4;
            int chp = (cQ >> 1) ^ (nn & 7);
            *(uint2*)((char*)xs + nn*256 + (chp << 4) + (cQ & 1)*8) = make_uint2(w0, w1);
        }
        // ---- B: issue next chunk's staging loads (hidden under C/D/E/F) ----
        if (chk + 1 < NCH) {
            const int gn1 = n_slab + (chk + 1) * PCH;
#pragma unroll
            for (int i = 0; i < 8; ++i) {
                int u = (t >> 2) + 128 * i, cQ = u >> 5, nQ = u & 31;
                float4 v = *(const float4*)(xb + (size_t)(4*cQ + r4) * NN + gn1 + 4*nQ);
                pf0[i] = f2bf(v.x) | (f2bf(v.y) << 16);
                pf1[i] = f2bf(v.z) | (f2bf(v.w) << 16);
            }
        }
        LDS_FENCE_BARRIER();   // #1: xs, xc visible

        // ---- C: logits D[k][n] = W x X ----
        f32x16 lacc;
#pragma unroll
        for (int i = 0; i < 16; ++i) lacc[i] = 0.f;
#pragma unroll
        for (int cs = 0; cs < 8; ++cs) {
            int chp = (2*cs + q) ^ (n_ & 7);
            short8 bf = *(const short8*)((const char*)xs + n_*256 + (chp << 4));
            lacc = __builtin_amdgcn_mfma_f32_32x32x16_bf16(wfrag[cs], bf, lacc, 0, 0, 0);
        }

        // ---- D: softmax over k, no max-sub (|logit| <~ 8, exp safe in fp32) ----
        float ssum = 0.f;
#pragma unroll
        for (int i = 0; i < 16; ++i) { float e2 = __expf(lacc[i]); lacc[i] = e2; ssum += e2; }
        ssum += __shfl_xor(ssum, 32);
        if (q == 0) redsm[kt][n_] = ssum;
        LDS_FENCE_BARRIER();   // #2: denom visible

        // ---- E: scale, store a -> al (aliased), accumulate asum ----
        float inv = 1.0f / (redsm[0][n_] + redsm[1][n_]);
#pragma unroll
        for (int i = 0; i < 16; ++i) {
            float a = lacc[i] * inv;
            asum_l[i] += a;
            int k_ = 32*kt + 4*q + (i & 3) + 8*(i >> 2);
            al[k_*128 + ((((n_ >> 3) ^ (k_ & 7)) << 3) | (n_ & 7))] = (unsigned short)f2bf(a);
        }
        LDS_FENCE_BARRIER();   // #3: al ready

        // ---- F: vlad D[c][k] += X x A^T, both operands from LDS ----
#pragma unroll
        for (int ns = 0; ns < 8; ++ns) {
            int ca = (2*ns + q) ^ (c2 & 7);
            short8 af = *(const short8*)((const char*)xc + c2*256 + (ca << 4));
            int cb = (2*ns + q) ^ (k2 & 7);
            short8 bf = *(const short8*)((const char*)al + k2*256 + (cb << 4));
            vacc = __builtin_amdgcn_mfma_f32_32x32x16_bf16(af, bf, vacc, 0, 0, 0);
        }
        LDS_FENCE_BARRIER();   // #4: LDS free for next chunk's staging writes
    }

    // ---- epilogue: vlad partials -> global atomics ----
    {
        float* vb = vlad + (size_t)b * KK * CC + (size_t)k2 * CC + 32*ct + 4*q;
#pragma unroll
        for (int i = 0; i < 16; ++i)
            atomicAdd(&vb[(i & 3) + 8*(i >> 2)], vacc[i]);
    }

    // ---- asum: butterfly over 32 pixel-lanes, cross-wave LDS, 64 atomics ----
#pragma unroll
    for (int i = 0; i < 16; ++i) {
        float v = asum_l[i];
        v += __shfl_xor(v, 1);  v += __shfl_xor(v, 2);  v += __shfl_xor(v, 4);
        v += __shfl_xor(v, 8);  v += __shfl_xor(v, 16);
        asum_l[i] = v;
    }
    if (ln == 0) {
#pragma unroll
        for (int i = 0; i < 16; ++i) asred[kt][q][i][nt] = asum_l[i];
    }
    __syncthreads();
    if (t < 64) {
        int kt_ = t >> 5, q_ = (t >> 4) & 1, r_ = t & 15;
        int k_ = 32*kt_ + 4*q_ + (r_ & 3) + 8*(r_ >> 2);
        float s = asred[kt_][q_][r_][0] + asred[kt_][q_][r_][1]
                + asred[kt_][q_][r_][2] + asred[kt_][q_][r_][3];
        atomicAdd(&asum_g[b * KK + k_], s);
    }
}

// ---------------- Phase 2: centroid subtract + intra + global L2 normalize ---
__global__ __launch_bounds__(256) void nv_phase2(
    float* __restrict__ vlad,        // [B][K][C] in/out (d_out)
    const float* __restrict__ asum,  // [B][K]
    const float* __restrict__ cent)  // [K][C]
{
    __shared__ float gred[4];
    const int b    = blockIdx.x;
    const int w    = threadIdx.x >> 6;   // wave 0..3 -> 16 rows each
    const int lane = threadIdx.x & 63;

    float v[32];
    float gsum = 0.f;
#pragma unroll
    for (int r = 0; r < 16; r++) {
        int k = w * 16 + r;
        float a  = asum[b * KK + k];
        float x0 = vlad[((size_t)b * KK + k) * CC + lane]      - a * cent[k * CC + lane];
        float x1 = vlad[((size_t)b * KK + k) * CC + lane + 64] - a * cent[k * CC + lane + 64];
        float ss = x0 * x0 + x1 * x1;
#pragma unroll
        for (int m = 1; m < 64; m <<= 1) ss += __shfl_xor(ss, m, 64);
        float rn = 1.0f / fmaxf(sqrtf(ss), 1e-12f);
        v[2 * r]     = x0 * rn;
        v[2 * r + 1] = x1 * rn;
        gsum += ss * rn * rn;
    }
    if (lane == 0) gred[w] = gsum;
    __syncthreads();
    float g  = gred[0] + gred[1] + gred[2] + gred[3];
    float gs = 1.0f / fmaxf(sqrtf(g), 1e-12f);
#pragma unroll
    for (int r = 0; r < 16; r++) {
        int k = w * 16 + r;
        vlad[((size_t)b * KK + k) * CC + lane]      = v[2 * r]     * gs;
        vlad[((size_t)b * KK + k) * CC + lane + 64] = v[2 * r + 1] * gs;
    }
}

extern "C" void kernel_launch(void* const* d_in, const int* in_sizes, int n_in,
                              void* d_out, int out_size, void* d_ws, size_t ws_size,
                              hipStream_t stream) {
    const float* x     = (const float*)d_in[0];
    const float* convw = (const float*)d_in[1];
    const float* cent  = (const float*)d_in[2];
    float* out  = (float*)d_out;
    float* asum = (float*)d_ws;   // B*K floats = 16 KiB

    hipMemsetAsync(out,  0, (size_t)BB * KK * CC * sizeof(float), stream);
    hipMemsetAsync(asum, 0, (size_t)BB * KK * sizeof(float), stream);

    nv_phase1<<<dim3(NN / SLAB, BB), 512, 0, stream>>>(x, convw, out, asum);
    nv_phase2<<<BB, 256, 0, stream>>>(out, asum, cent);
}

// Round 7
// 48.877 us; speedup vs baseline: 3.5874x; 3.2548x over previous
//
#include <hip/hip_runtime.h>
#include <math.h>

#define BB 64
#define CC 128
#define KK 64
#define NN 4096
#define PCH 128            // pixels per chunk
#define NCH 8              // chunks per block
#define SLAB (PCH*NCH)     // 1024 pixels per block
#define VSTRIDE ((size_t)BB*KK*CC)   // one vlad partial copy (524288 floats)

typedef __attribute__((ext_vector_type(8))) short short8;
typedef __attribute__((ext_vector_type(16))) float f32x16;

// fp32 -> bf16 bits, round-to-nearest-even
__device__ __forceinline__ unsigned f2bf(float f) {
    unsigned u = __float_as_uint(f);
    return (u + 0x7fffu + ((u >> 16) & 1u)) >> 16;
}

__device__ __forceinline__ short8 pack8(float4 a, float4 b) {
    short8 r;
    r[0]=(short)f2bf(a.x); r[1]=(short)f2bf(a.y); r[2]=(short)f2bf(a.z); r[3]=(short)f2bf(a.w);
    r[4]=(short)f2bf(b.x); r[5]=(short)f2bf(b.y); r[6]=(short)f2bf(b.z); r[7]=(short)f2bf(b.w);
    return r;
}

// LDS-only fence barrier: drains ds ops for cross-wave visibility but leaves
// global loads (vmcnt) in flight across the barrier (prefetch survives).
#define LDS_FENCE_BARRIER() do {                                  \
    asm volatile("s_waitcnt lgkmcnt(0)" ::: "memory");            \
    __builtin_amdgcn_s_barrier();                                 \
} while (0)

// ---------------- Phase 1: logits -> softmax -> vlad partials (MFMA bf16) ----
// MFMA 32x32x16 layouts (verified round 2, absmax 1.2e-4 PASS):
//   A[m][k]: lane m=l&31, k=8*(l>>5)+j ; B[k][n]: lane n=l&31, k=8*(l>>5)+j
//   C/D: col=l&31, row=(r&3)+8*(r>>2)+4*(l>>5)
// LDS 16B-chunk XOR swizzle: chunk' = chunk ^ (row & 7)
// NO global atomics: per-slab partials via plain stores (round-7 fix).
__global__ __launch_bounds__(512, 2) void nv_phase1(
    const float* __restrict__ x,      // [B][C][N]
    const float* __restrict__ convw,  // [K][C]
    float* __restrict__ vlad,         // [B][K][C]  slab-0 partial (d_out)
    float* __restrict__ wsf)          // slabs 1..3 vlad partials + 4 asum partials
{
    __shared__ alignas(16) unsigned short xs[PCH*CC];  // 32 KB bf16 x, [n][c], swizzled
    __shared__ alignas(16) unsigned short xc[CC*PCH];  // 32 KB bf16 x, [c][n], swizzled
    __shared__ float redsm[2][PCH];                    // softmax denom cross-wave
    __shared__ float asred[2][2][16][4];               // [kt][q][r][nt]

    unsigned short* al = xs;   // a[k][n] bf16 (16 KB) aliases xs rows 0..63:
                               // xs dead after logits; al dead before next stage.

    const int t  = threadIdx.x;
    const int b  = blockIdx.y;
    const int slab = blockIdx.x;
    const int n_slab = slab * SLAB;
    const int l   = t & 63;
    const int wid = t >> 6;
    const int ln  = l & 31;
    const int q   = l >> 5;
    const int kt  = wid & 1;          // logits k-tile
    const int nt  = wid >> 1;         // logits n-tile
    const int ct  = wid & 3;          // vlad c-tile
    const int kt2 = wid >> 2;         // vlad k-tile
    const int r4  = t & 3;

    const float* xb = x + (size_t)b * CC * NN;
    const int n_ = ln + 32*nt;        // softmax pixel (chunk-local)
    const int c2 = ln + 32*ct;        // vlad A row (channel)
    const int k2 = ln + 32*kt2;       // vlad B row (cluster)

    // ---- prologue: issue chunk-0 staging loads, held RAW (converted in A) ----
    float4 pf[8];
#pragma unroll
    for (int i = 0; i < 8; ++i) {
        int u = (t >> 2) + 128 * i, cQ = u >> 5, nQ = u & 31;
        pf[i] = *(const float4*)(xb + (size_t)(4*cQ + r4) * NN + n_slab + 4*nQ);
    }

    // ---- preload conv_w fragments (A of logits), reused for all chunks ----
    short8 wfrag[8];
    {
        const float* wr = convw + (size_t)(ln + 32*kt) * CC + 8*q;
#pragma unroll
        for (int cs = 0; cs < 8; ++cs) {
            float4 a  = *(const float4*)(wr + 16*cs);
            float4 bb = *(const float4*)(wr + 16*cs + 4);
            wfrag[cs] = pack8(a, bb);
        }
    }

    f32x16 vacc;
#pragma unroll
    for (int i = 0; i < 16; ++i) vacc[i] = 0.f;
    float asum_l[16];
#pragma unroll
    for (int i = 0; i < 16; ++i) asum_l[i] = 0.f;

#pragma unroll 1
    for (int chk = 0; chk < NCH; ++chk) {
        // ---- A: convert pf -> bf16, write xs[n][c] + xc[c][n] ----
#pragma unroll
        for (int i = 0; i < 8; ++i) {
            int u = (t >> 2) + 128 * i, cQ = u >> 5, nQ = u & 31;
            unsigned d0 = f2bf(pf[i].x) | (f2bf(pf[i].y) << 16);
            unsigned d1 = f2bf(pf[i].z) | (f2bf(pf[i].w) << 16);
            // xc: straight write, 4 consecutive n at row c
            int c = 4*cQ + r4;
            *(uint2*)((char*)xc + c*256 + ((((nQ >> 1) ^ (c & 7)) << 4) | ((nQ & 1) * 8)))
                = make_uint2(d0, d1);
            // xs: quad 4x4 shuffle transpose (verified round 2)
            unsigned q0 = (unsigned)__shfl_xor((int)d0, 1);
            unsigned q1 = (unsigned)__shfl_xor((int)d1, 1);
            unsigned e, f;
            if (r4 & 1) { e = (q0 >> 16) | (d0 & 0xffff0000u);
                          f = (q1 >> 16) | (d1 & 0xffff0000u); }
            else        { e = (d0 & 0xffffu) | (q0 << 16);
                          f = (d1 & 0xffffu) | (q1 << 16); }
            unsigned s2 = (unsigned)__shfl_xor((int)((r4 & 2) ? e : f), 2);
            unsigned w0 = (r4 & 2) ? s2 : e;
            unsigned w1 = (r4 & 2) ? f : s2;
            int nn  = 4*nQ + r4;
            int chp = (cQ >> 1) ^ (nn & 7);
            *(uint2*)((char*)xs + nn*256 + (chp << 4) + (cQ & 1)*8) = make_uint2(w0, w1);
        }
        // ---- B: issue next chunk's staging loads (consumed in next A) ----
        if (chk + 1 < NCH) {
            const int gn1 = n_slab + (chk + 1) * PCH;
#pragma unroll
            for (int i = 0; i < 8; ++i) {
                int u = (t >> 2) + 128 * i, cQ = u >> 5, nQ = u & 31;
                pf[i] = *(const float4*)(xb + (size_t)(4*cQ + r4) * NN + gn1 + 4*nQ);
            }
        }
        LDS_FENCE_BARRIER();   // #1: xs, xc visible

        // ---- C: logits D[k][n] = W x X ----
        f32x16 lacc;
#pragma unroll
        for (int i = 0; i < 16; ++i) lacc[i] = 0.f;
#pragma unroll
        for (int cs = 0; cs < 8; ++cs) {
            int chp = (2*cs + q) ^ (n_ & 7);
            short8 bf = *(const short8*)((const char*)xs + n_*256 + (chp << 4));
            lacc = __builtin_amdgcn_mfma_f32_32x32x16_bf16(wfrag[cs], bf, lacc, 0, 0, 0);
        }

        // ---- D: softmax over k, no max-sub (|logit| <~ 8, exp safe in fp32) ----
        float ssum = 0.f;
#pragma unroll
        for (int i = 0; i < 16; ++i) { float e2 = __expf(lacc[i]); lacc[i] = e2; ssum += e2; }
        ssum += __shfl_xor(ssum, 32);
        if (q == 0) redsm[kt][n_] = ssum;
        LDS_FENCE_BARRIER();   // #2: denom visible

        // ---- E: scale, store a -> al (aliased), accumulate asum ----
        float inv = 1.0f / (redsm[0][n_] + redsm[1][n_]);
#pragma unroll
        for (int i = 0; i < 16; ++i) {
            float a = lacc[i] * inv;
            asum_l[i] += a;
            int k_ = 32*kt + 4*q + (i & 3) + 8*(i >> 2);
            al[k_*128 + ((((n_ >> 3) ^ (k_ & 7)) << 3) | (n_ & 7))] = (unsigned short)f2bf(a);
        }
        LDS_FENCE_BARRIER();   // #3: al ready

        // ---- F: vlad D[c][k] += X x A^T, both operands from LDS ----
#pragma unroll
        for (int ns = 0; ns < 8; ++ns) {
            int ca = (2*ns + q) ^ (c2 & 7);
            short8 af = *(const short8*)((const char*)xc + c2*256 + (ca << 4));
            int cb = (2*ns + q) ^ (k2 & 7);
            short8 bf = *(const short8*)((const char*)al + k2*256 + (cb << 4));
            vacc = __builtin_amdgcn_mfma_f32_32x32x16_bf16(af, bf, vacc, 0, 0, 0);
        }
        LDS_FENCE_BARRIER();   // #4: LDS free for next chunk's staging writes
    }

    // ---- epilogue: vlad partial tile -> plain float4 stores (NO atomics) ----
    {
        float* base = (slab == 0)
            ? vlad + (size_t)b * KK * CC
            : wsf + (size_t)(slab - 1) * VSTRIDE + (size_t)b * KK * CC;
        float* vb = base + (size_t)k2 * CC + 32*ct + 4*q;
#pragma unroll
        for (int g = 0; g < 4; ++g) {
            float4 o;
            o.x = vacc[4*g+0]; o.y = vacc[4*g+1]; o.z = vacc[4*g+2]; o.w = vacc[4*g+3];
            *(float4*)(vb + 8*g) = o;   // q0+q1 lanes tile the full 64B lines
        }
    }

    // ---- asum: butterfly over 32 pixel-lanes, cross-wave LDS, plain stores ----
#pragma unroll
    for (int i = 0; i < 16; ++i) {
        float v = asum_l[i];
        v += __shfl_xor(v, 1);  v += __shfl_xor(v, 2);  v += __shfl_xor(v, 4);
        v += __shfl_xor(v, 8);  v += __shfl_xor(v, 16);
        asum_l[i] = v;
    }
    if (ln == 0) {
#pragma unroll
        for (int i = 0; i < 16; ++i) asred[kt][q][i][nt] = asum_l[i];
    }
    __syncthreads();
    if (t < 64) {
        int kt_ = t >> 5, q_ = (t >> 4) & 1, r_ = t & 15;
        int k_ = 32*kt_ + 4*q_ + (r_ & 3) + 8*(r_ >> 2);
        float s = asred[kt_][q_][r_][0] + asred[kt_][q_][r_][1]
                + asred[kt_][q_][r_][2] + asred[kt_][q_][r_][3];
        wsf[3 * VSTRIDE + (size_t)slab * BB * KK + b * KK + k_] = s;
    }
}

// ------- Phase 2: sum 4 partials + centroid subtract + intra/global L2 -------
__global__ __launch_bounds__(256) void nv_phase2(
    float* __restrict__ vlad,        // [B][K][C] in: slab-0 partial / out: result
    const float* __restrict__ wsf,   // slabs 1..3 vlad partials + 4 asum partials
    const float* __restrict__ cent)  // [K][C]
{
    __shared__ float gred[4];
    const int b    = blockIdx.x;
    const int w    = threadIdx.x >> 6;   // wave 0..3 -> 16 rows each
    const int lane = threadIdx.x & 63;
    const float* ap = wsf + 3 * VSTRIDE; // [4][B][K]

    float v[32];
    float gsum = 0.f;
#pragma unroll
    for (int r = 0; r < 16; r++) {
        int k = w * 16 + r;
        float a = ap[0*BB*KK + b*KK + k] + ap[1*BB*KK + b*KK + k]
                + ap[2*BB*KK + b*KK + k] + ap[3*BB*KK + b*KK + k];
        size_t o = ((size_t)b * KK + k) * CC + lane;
        float x0 = vlad[o]      + wsf[o]      + wsf[VSTRIDE + o]      + wsf[2*VSTRIDE + o];
        float x1 = vlad[o + 64] + wsf[o + 64] + wsf[VSTRIDE + o + 64] + wsf[2*VSTRIDE + o + 64];
        x0 -= a * cent[k * CC + lane];
        x1 -= a * cent[k * CC + lane + 64];
        float ss = x0 * x0 + x1 * x1;
#pragma unroll
        for (int m = 1; m < 64; m <<= 1) ss += __shfl_xor(ss, m, 64);
        float rn = 1.0f / fmaxf(sqrtf(ss), 1e-12f);
        v[2 * r]     = x0 * rn;
        v[2 * r + 1] = x1 * rn;
        gsum += ss * rn * rn;
    }
    if (lane == 0) gred[w] = gsum;
    __syncthreads();
    float g  = gred[0] + gred[1] + gred[2] + gred[3];
    float gs = 1.0f / fmaxf(sqrtf(g), 1e-12f);
#pragma unroll
    for (int r = 0; r < 16; r++) {
        int k = w * 16 + r;
        vlad[((size_t)b * KK + k) * CC + lane]      = v[2 * r]     * gs;
        vlad[((size_t)b * KK + k) * CC + lane + 64] = v[2 * r + 1] * gs;
    }
}

extern "C" void kernel_launch(void* const* d_in, const int* in_sizes, int n_in,
                              void* d_out, int out_size, void* d_ws, size_t ws_size,
                              hipStream_t stream) {
    const float* x     = (const float*)d_in[0];
    const float* convw = (const float*)d_in[1];
    const float* cent  = (const float*)d_in[2];
    float* out = (float*)d_out;
    float* wsf = (float*)d_ws;   // 3*VSTRIDE vlad partials + 4*B*K asum = ~6.4 MB

    nv_phase1<<<dim3(NN / SLAB, BB), 512, 0, stream>>>(x, convw, out, wsf);
    nv_phase2<<<BB, 256, 0, stream>>>(out, wsf, cent);
}